// Round 8
// baseline (1412.298 us; speedup 1.0000x reference)
//
#include <hip/hip_runtime.h>
#include <hip/hip_bf16.h>
#include <cstdint>

// Problem constants (B=4, S=2048, H=2048, I=1024, E=8, K=2)
#define T_TOKENS 8192
#define H_DIM 2048
#define I_DIM 1024
#define N_EXPERTS 8
#define PAIRS (T_TOKENS * 2)
#define TOT_TILES 144            // sum_b ceil(n_b/128) <= 16384/128 + 16
#define TOT_ROWS (TOT_TILES * 128)

using f32x4 = __attribute__((ext_vector_type(4))) float;
using bfv   = __attribute__((ext_vector_type(8))) short;   // MFMA a/b frag (8 bf16)
using u16x8 = __attribute__((ext_vector_type(8))) unsigned short;

typedef __attribute__((address_space(3))) unsigned int lds_u32;
typedef __attribute__((address_space(1))) unsigned int glb_u32;

__device__ __forceinline__ void gll16(const void* g, void* l) {
  __builtin_amdgcn_global_load_lds((const glb_u32*)g, (lds_u32*)l, 16, 0, 0);
}
#define SB0() __builtin_amdgcn_sched_barrier(0)
#define BAR() __builtin_amdgcn_s_barrier()

__device__ inline unsigned short f2bf(float f) {
  unsigned int u = __float_as_uint(f);
  u += 0x7FFFu + ((u >> 16) & 1u);          // RTN-even
  return (unsigned short)(u >> 16);
}

// ---------------- fp32 -> bf16 bulk convert ----------------
__global__ __launch_bounds__(256) void moe_convert_kernel(
    const float* __restrict__ src, unsigned short* __restrict__ dst, int n8) {
  int i = blockIdx.x * 256 + threadIdx.x;
  if (i >= n8) return;
  size_t o = (size_t)i * 8;
  f32x4 a = *reinterpret_cast<const f32x4*>(src + o);
  f32x4 b = *reinterpret_cast<const f32x4*>(src + o + 4);
  u16x8 r = {f2bf(a[0]), f2bf(a[1]), f2bf(a[2]), f2bf(a[3]),
             f2bf(b[0]), f2bf(b[1]), f2bf(b[2]), f2bf(b[3])};
  *reinterpret_cast<u16x8*>(dst + o) = r;
}

// ---------------- Router: RMSNorm folded into logits, softmax, top-2 (fp32) ----------------
// Also writes the bf16 copy of X (free: X is being read anyway).
__global__ __launch_bounds__(256) void moe_router_kernel(
    const float* __restrict__ X, const float* __restrict__ norm_w,
    const float* __restrict__ rw, float* __restrict__ probs,
    float* __restrict__ topw, int* __restrict__ topi,
    unsigned int* __restrict__ counts, unsigned short* __restrict__ Xb) {
  int t = blockIdx.x;
  int tid = threadIdx.x;
  const float* x = X + (size_t)t * H_DIM;
  int base = tid * 8;
  f32x4 v0 = *reinterpret_cast<const f32x4*>(x + base);
  f32x4 v1 = *reinterpret_cast<const f32x4*>(x + base + 4);
  u16x8 bx = {f2bf(v0[0]), f2bf(v0[1]), f2bf(v0[2]), f2bf(v0[3]),
              f2bf(v1[0]), f2bf(v1[1]), f2bf(v1[2]), f2bf(v1[3])};
  *reinterpret_cast<u16x8*>(Xb + (size_t)t * H_DIM + base) = bx;
  f32x4 nw0 = *reinterpret_cast<const f32x4*>(norm_w + base);
  f32x4 nw1 = *reinterpret_cast<const f32x4*>(norm_w + base + 4);
  float vals[9];
  vals[0] = v0[0]*v0[0] + v0[1]*v0[1] + v0[2]*v0[2] + v0[3]*v0[3]
          + v1[0]*v1[0] + v1[1]*v1[1] + v1[2]*v1[2] + v1[3]*v1[3];
  f32x4 a0 = v0 * nw0, a1 = v1 * nw1;
#pragma unroll
  for (int e = 0; e < 8; ++e) {
    const float* r = rw + e * H_DIM + base;
    f32x4 r0 = *reinterpret_cast<const f32x4*>(r);
    f32x4 r1 = *reinterpret_cast<const f32x4*>(r + 4);
    f32x4 d = a0 * r0 + a1 * r1;
    vals[e + 1] = d[0] + d[1] + d[2] + d[3];
  }
#pragma unroll
  for (int v = 0; v < 9; ++v) {
    float s = vals[v];
#pragma unroll
    for (int off = 32; off > 0; off >>= 1) s += __shfl_xor(s, off);
    vals[v] = s;
  }
  __shared__ float red[4][9];
  int lane = tid & 63, w = tid >> 6;
  if (lane == 0) {
#pragma unroll
    for (int v = 0; v < 9; ++v) red[w][v] = vals[v];
  }
  __syncthreads();
  if (tid == 0) {
    float tot[9];
#pragma unroll
    for (int v = 0; v < 9; ++v) tot[v] = red[0][v] + red[1][v] + red[2][v] + red[3][v];
    float rs = rsqrtf(tot[0] / (float)H_DIM + 1e-6f);
    float lg[8], mx = -1e30f;
#pragma unroll
    for (int e = 0; e < 8; ++e) { lg[e] = tot[e + 1] * rs; mx = fmaxf(mx, lg[e]); }
    float pe[8], sum = 0.f;
#pragma unroll
    for (int e = 0; e < 8; ++e) { pe[e] = expf(lg[e] - mx); sum += pe[e]; }
    float inv = 1.f / sum;
#pragma unroll
    for (int e = 0; e < 8; ++e) { pe[e] *= inv; probs[t * 8 + e] = pe[e]; }
    int b1 = 0; float p1 = pe[0];
#pragma unroll
    for (int e = 1; e < 8; ++e) if (pe[e] > p1) { p1 = pe[e]; b1 = e; }
    int b2 = -1; float p2 = -1.f;
#pragma unroll
    for (int e = 0; e < 8; ++e) if (e != b1 && pe[e] > p2) { p2 = pe[e]; b2 = e; }
    float wsum = p1 + p2;
    topw[t * 2] = p1 / wsum;
    topw[t * 2 + 1] = p2 / wsum;
    topi[t * 2] = b1;
    topi[t * 2 + 1] = b2;
    atomicAdd(&counts[b1], 1u);        // slot-0 bucket
    atomicAdd(&counts[8 + b2], 1u);    // slot-1 bucket
  }
}

// ---------------- importance[e] = sum_t probs[t,e] ----------------
__global__ __launch_bounds__(256) void moe_importance_kernel(
    const float* __restrict__ probs, float* __restrict__ impSum) {
  int e = blockIdx.x, tid = threadIdx.x;
  float s = 0.f;
  for (int t = tid; t < T_TOKENS; t += 256) s += probs[t * 8 + e];
  __shared__ float red[256];
  red[tid] = s;
  __syncthreads();
  for (int st = 128; st > 0; st >>= 1) {
    if (tid < st) red[tid] += red[tid + st];
    __syncthreads();
  }
  if (tid == 0) impSum[e] = red[0];
}

// ---------------- tile offsets + aux loss ----------------
__global__ void moe_offsets_aux_kernel(const unsigned int* __restrict__ counts,
                                       const float* __restrict__ impSum,
                                       int* __restrict__ tileOff,
                                       float* __restrict__ out_aux) {
  if (threadIdx.x == 0 && blockIdx.x == 0) {
    int acc = 0;
    for (int b = 0; b < 16; ++b) {
      tileOff[b] = acc;
      acc += (int)((counts[b] + 127u) >> 7);
    }
    tileOff[16] = acc;
    float a = 0.f;
    for (int e = 0; e < 8; ++e) {
      float load = (float)(counts[e] + counts[8 + e]) / (float)PAIRS;
      a += (impSum[e] / (float)T_TOKENS) * load;
    }
    out_aux[0] = a * (float)N_EXPERTS;
  }
}

// ---------------- bucket pairs (expert x slot) ----------------
__global__ __launch_bounds__(256) void moe_assign_kernel(
    const int* __restrict__ topi, const int* __restrict__ tileOff,
    unsigned int* __restrict__ cursors, int* __restrict__ row2pair) {
  int p = blockIdx.x * 256 + threadIdx.x;
  if (p >= PAIRS) return;
  int b = topi[p] + 8 * (p & 1);
  unsigned int pos = atomicAdd(&cursors[b], 1u);
  row2pair[tileOff[b] * 128 + (int)pos] = p;
}

// ======================= GEMM stages =======================
// Geometry: BM=128 rows, BN=256 cols, BK=32, 256 threads = 4 waves; wave w owns
// cols [w*64, w*64+64) x 128 rows -> per K-step 8 A-frags + 4 B-frags -> 32 MFMA.
// LDS layout is FRAGMENT-MAJOR: each 16-row MFMA subtile stored as 64
// consecutive 16B chunks indexed by lane (chunk = sub*64 + kc*16 + lrow).
// Reads are base + lane*16 (contiguous per wave -> conflict-free); the
// permutation lives in the per-lane *global source* address of gll16
// (LDS dest must stay linear: wave-uniform base + lane*16).
// A region: chunks [0,512) at short-offset 0; B region: [0,1024) at 4096.
// Pipeline: prefetch next K-step (6 gll16/thread), s_waitcnt vmcnt(6),
// s_barrier, MFMA cluster (setprio 1), s_barrier. Dbuf 48KB -> 3 blocks/CU.
// Stage A K-extent: H_DIM/32 = 64 steps.  Stage B: I_DIM/32 = 32 steps.

// ---------------- Stage A: P = silu(X@gate^T) * (X@up^T) ----------------
// Concat-N: wave cols [0,32) = gate, [32,64) = up of the SAME I-columns ->
// silu fuse fully in-register (acc[m][n] g / acc[m][n+2] u).
__global__ __launch_bounds__(256, 3) void moe_stage_a(
    const unsigned short* __restrict__ Xb,
    const unsigned short* __restrict__ Wg, const unsigned short* __restrict__ Wu,
    const int* __restrict__ row2pair, const int* __restrict__ tileOff,
    unsigned int* __restrict__ workCtr, unsigned short* __restrict__ P) {
  __shared__ __align__(16) unsigned short sAB[2][12288];
  __shared__ int sTok[128];
  __shared__ int sWork;
  const int tid = threadIdx.x;
  const int lane = tid & 63, w = tid >> 6;
  const int lrow = lane & 15, grp = lane >> 4;
  const int nTiles = tileOff[16];
  const int nWork = nTiles * 8;

  for (;;) {
    if (tid == 0) sWork = (int)atomicAdd(workCtr, 1u);
    __syncthreads();
    const int item = sWork;
    if (item >= nWork) break;
    const int mt = item % nTiles;
    const int nt = item / nTiles;       // I-block [nt*128, nt*128+128)
    int b = 0;
#pragma unroll
    for (int k = 1; k < 16; ++k) if (tileOff[k] <= mt) b = k;
    const int e = b & 7;
    const int row0 = mt * 128;
    if (tid < 128) {
      int pr = row2pair[row0 + tid];
      sTok[tid] = (pr >= 0) ? (pr >> 1) : 0;
    }
    __syncthreads();

    const size_t wbase = (size_t)e * ((size_t)I_DIM * H_DIM);
    const unsigned short* src[6];
    // A chunks: idx=[0,512): sub=idx>>6, l=idx&63 -> row=sub*16+(l&15), kc=l>>4
#pragma unroll
    for (int i = 0; i < 2; ++i) {
      int idx = i * 256 + tid;
      int l = idx & 63;
      int row = (idx >> 6) * 16 + (l & 15);
      src[i] = Xb + (size_t)sTok[row] * H_DIM + ((l >> 4) << 3);
    }
    // B chunks: idx=[0,1024): brow=sub*16+(l&15) in [0,256); brow>>6 = wave col
    // group wq; within: r6<32 -> gate col, r6>=32 -> up col (same I index).
#pragma unroll
    for (int i = 2; i < 6; ++i) {
      int idx = (i - 2) * 256 + tid;
      int l = idx & 63;
      int brow = (idx >> 6) * 16 + (l & 15);
      int wq = brow >> 6, r6 = brow & 63;
      int irow = nt * 128 + wq * 32 + (r6 & 31);
      const unsigned short* basep = (r6 >> 5) ? Wu : Wg;
      src[i] = basep + wbase + (size_t)irow * H_DIM + ((l >> 4) << 3);
    }

    f32x4 acc[8][4] = {};

#pragma unroll
    for (int i = 0; i < 6; ++i)
      gll16(src[i], (void*)&sAB[0][(i * 256 + tid) * 8]);

    int cur = 0;
#pragma unroll 1
    for (int kk = 0; kk < 64; ++kk) {          // 64 * BK32 = 2048 = H_DIM
      if (kk < 63) {
#pragma unroll
        for (int i = 0; i < 6; ++i)
          gll16(src[i] + ((kk + 1) << 5), (void*)&sAB[cur ^ 1][(i * 256 + tid) * 8]);
        SB0();
        asm volatile("s_waitcnt vmcnt(6)" ::: "memory");
      } else {
        asm volatile("s_waitcnt vmcnt(0)" ::: "memory");
      }
      SB0();
      BAR();
      SB0();
      bfv af[8], bf[4];
#pragma unroll
      for (int m = 0; m < 8; ++m)
        af[m] = *reinterpret_cast<const bfv*>(&sAB[cur][(m * 64 + lane) * 8]);
#pragma unroll
      for (int n = 0; n < 4; ++n)
        bf[n] = *reinterpret_cast<const bfv*>(&sAB[cur][4096 + ((w * 4 + n) * 64 + lane) * 8]);
      __builtin_amdgcn_s_setprio(1);
#pragma unroll
      for (int m = 0; m < 8; ++m)
#pragma unroll
        for (int n = 0; n < 4; ++n)
          acc[m][n] = __builtin_amdgcn_mfma_f32_16x16x32_bf16(af[m], bf[n], acc[m][n], 0, 0, 0);
      __builtin_amdgcn_s_setprio(0);
      SB0();
      BAR();
      cur ^= 1;
    }

    // epilogue: silu fuse in-register; C/D: row = grp*4+j, col = lrow
#pragma unroll
    for (int m = 0; m < 8; ++m) {
#pragma unroll
      for (int n = 0; n < 2; ++n) {
#pragma unroll
        for (int j = 0; j < 4; ++j) {
          float g = acc[m][n][j];
          float uu = acc[m][n + 2][j];
          float pv = (g / (1.f + expf(-g))) * uu;
          int row = row0 + m * 16 + grp * 4 + j;
          int col = nt * 128 + w * 32 + n * 16 + lrow;
          P[(size_t)row * I_DIM + col] = f2bf(pv);
        }
      }
    }
  }
}

// ---------------- Stage B: O = P @ down^T, weighted scatter to out ----------------
// phase 0 (slot-0 buckets): out = 4*w*o ; phase 1 (slot-1): out += 4*w*o.
__global__ __launch_bounds__(256, 3) void moe_stage_b(
    const unsigned short* __restrict__ Pb, const unsigned short* __restrict__ Wd,
    const int* __restrict__ row2pair, const int* __restrict__ tileOff,
    const float* __restrict__ topw, unsigned int* __restrict__ workCtr,
    float* __restrict__ out, int phase) {
  __shared__ __align__(16) unsigned short sAB[2][12288];
  __shared__ int sPair[128];
  __shared__ int sWork;
  const int tid = threadIdx.x;
  const int lane = tid & 63, w = tid >> 6;
  const int lrow = lane & 15, grp = lane >> 4;
  const int t0 = phase ? tileOff[8] : 0;
  const int t1 = phase ? tileOff[16] : tileOff[8];
  const int nTiles = t1 - t0;
  const int nWork = nTiles * 8;

  for (;;) {
    if (tid == 0) sWork = (int)atomicAdd(workCtr, 1u);
    __syncthreads();
    const int item = sWork;
    if (item >= nWork) break;
    const int mt = t0 + item % nTiles;
    const int nt = item / nTiles;       // H-block [nt*256, nt*256+256)
    int b = 0;
#pragma unroll
    for (int k = 1; k < 16; ++k) if (tileOff[k] <= mt) b = k;
    const int e = b & 7;
    const int row0 = mt * 128, h0 = nt * 256;
    if (tid < 128) sPair[tid] = row2pair[row0 + tid];
    __syncthreads();

    const unsigned short* src[6];
#pragma unroll
    for (int i = 0; i < 2; ++i) {
      int idx = i * 256 + tid;
      int l = idx & 63;
      int row = (idx >> 6) * 16 + (l & 15);
      src[i] = Pb + (size_t)(row0 + row) * I_DIM + ((l >> 4) << 3);
    }
#pragma unroll
    for (int i = 2; i < 6; ++i) {
      int idx = (i - 2) * 256 + tid;
      int l = idx & 63;
      int brow = (idx >> 6) * 16 + (l & 15);
      src[i] = Wd + (size_t)e * ((size_t)H_DIM * I_DIM) +
               (size_t)(h0 + brow) * I_DIM + ((l >> 4) << 3);
    }

    f32x4 acc[8][4] = {};

#pragma unroll
    for (int i = 0; i < 6; ++i)
      gll16(src[i], (void*)&sAB[0][(i * 256 + tid) * 8]);

    int cur = 0;
#pragma unroll 1
    for (int kk = 0; kk < 32; ++kk) {          // 32 * BK32 = 1024 = I_DIM
      if (kk < 31) {
#pragma unroll
        for (int i = 0; i < 6; ++i)
          gll16(src[i] + ((kk + 1) << 5), (void*)&sAB[cur ^ 1][(i * 256 + tid) * 8]);
        SB0();
        asm volatile("s_waitcnt vmcnt(6)" ::: "memory");
      } else {
        asm volatile("s_waitcnt vmcnt(0)" ::: "memory");
      }
      SB0();
      BAR();
      SB0();
      bfv af[8], bf[4];
#pragma unroll
      for (int m = 0; m < 8; ++m)
        af[m] = *reinterpret_cast<const bfv*>(&sAB[cur][(m * 64 + lane) * 8]);
#pragma unroll
      for (int n = 0; n < 4; ++n)
        bf[n] = *reinterpret_cast<const bfv*>(&sAB[cur][4096 + ((w * 4 + n) * 64 + lane) * 8]);
      __builtin_amdgcn_s_setprio(1);
#pragma unroll
      for (int m = 0; m < 8; ++m)
#pragma unroll
        for (int n = 0; n < 4; ++n)
          acc[m][n] = __builtin_amdgcn_mfma_f32_16x16x32_bf16(af[m], bf[n], acc[m][n], 0, 0, 0);
      __builtin_amdgcn_s_setprio(0);
      SB0();
      BAR();
      cur ^= 1;
    }

#pragma unroll
    for (int m = 0; m < 8; ++m) {
#pragma unroll
      for (int j = 0; j < 4; ++j) {
        int rl = m * 16 + grp * 4 + j;
        int pr = sPair[rl];
        if (pr < 0) continue;
        float wgt = topw[pr] * 4.f;   // SCALING = E/K
        float* orow = out + (size_t)(pr >> 1) * H_DIM + h0 + w * 64 + lrow;
        if (phase) {
#pragma unroll
          for (int n = 0; n < 4; ++n) orow[n * 16] += wgt * acc[m][n][j];
        } else {
#pragma unroll
          for (int n = 0; n < 4; ++n) orow[n * 16] = wgt * acc[m][n][j];
        }
      }
    }
  }
}

// ---------------- launch ----------------
// ws layout (bytes), REQ = 138,879,488 (proven available in round 2):
//   P        @ 0           : 18432*1024*2 = 37,748,736
//   probs    @ 37,748,736  : 262,144
//   topw     @ 38,010,880  : 65,536
//   topi     @ 38,076,416  : 65,536
//   row2pair @ 38,141,952  : 73,728
//   ctrl     @ 38,215,680  : 512  (counts[16] cursors[16] impSum[8] tileOff[17] workCtrs@384)
//   W1       @ 38,216,192  : 33,554,432  (gate bf16; reused for down bf16)
//   W2       @ 71,770,624  : 33,554,432  (up bf16)
//   Xb       @ 105,325,056 : 33,554,432  (X bf16)
extern "C" void kernel_launch(void* const* d_in, const int* in_sizes, int n_in,
                              void* d_out, int out_size, void* d_ws, size_t ws_size,
                              hipStream_t stream) {
  const float* X = (const float*)d_in[0];
  const float* norm_w = (const float*)d_in[1];
  const float* router_w = (const float*)d_in[2];
  const float* gate_w = (const float*)d_in[3];
  const float* up_w = (const float*)d_in[4];
  const float* down_w = (const float*)d_in[5];
  float* out = (float*)d_out;

  char* ws = (char*)d_ws;
  unsigned short* P = (unsigned short*)(ws);
  float* probs = (float*)(ws + 37748736);
  float* topw = (float*)(ws + 38010880);
  int* topi = (int*)(ws + 38076416);
  int* row2pair = (int*)(ws + 38141952);
  char* ctrl = ws + 38215680;
  unsigned int* counts = (unsigned int*)(ctrl);
  unsigned int* cursors = (unsigned int*)(ctrl + 64);
  float* impSum = (float*)(ctrl + 128);
  int* tileOff = (int*)(ctrl + 192);
  unsigned int* wcA = (unsigned int*)(ctrl + 384);
  unsigned int* wcB0 = (unsigned int*)(ctrl + 388);
  unsigned int* wcB1 = (unsigned int*)(ctrl + 392);
  unsigned short* W1 = (unsigned short*)(ws + 38216192);   // gate, then down
  unsigned short* W2 = (unsigned short*)(ws + 71770624);   // up
  unsigned short* Xb = (unsigned short*)(ws + 105325056);

  hipMemsetAsync(ctrl, 0, 512, stream);
  hipMemsetAsync(row2pair, 0xFF, (size_t)TOT_ROWS * 4, stream);

  const int N8 = (N_EXPERTS * I_DIM * H_DIM) / 8;   // 2,097,152
  moe_convert_kernel<<<N8 / 256, 256, 0, stream>>>(gate_w, W1, N8);
  moe_convert_kernel<<<N8 / 256, 256, 0, stream>>>(up_w, W2, N8);

  moe_router_kernel<<<T_TOKENS, 256, 0, stream>>>(X, norm_w, router_w, probs, topw, topi,
                                                  counts, Xb);
  moe_importance_kernel<<<N_EXPERTS, 256, 0, stream>>>(probs, impSum);
  moe_offsets_aux_kernel<<<1, 64, 0, stream>>>(counts, impSum, tileOff, out + 16777216);
  moe_assign_kernel<<<PAIRS / 256, 256, 0, stream>>>(topi, tileOff, cursors, row2pair);

  moe_stage_a<<<768, 256, 0, stream>>>(Xb, W1, W2, row2pair, tileOff, wcA, P);
  moe_convert_kernel<<<N8 / 256, 256, 0, stream>>>(down_w, W1, N8);
  moe_stage_b<<<768, 256, 0, stream>>>(P, W1, row2pair, tileOff, topw, wcB0, out, 0);
  moe_stage_b<<<768, 256, 0, stream>>>(P, W1, row2pair, tileOff, topw, wcB1, out, 1);
}

// Round 9
// 715.713 us; speedup vs baseline: 1.9733x; 1.9733x over previous
//
#include <hip/hip_runtime.h>
#include <hip/hip_bf16.h>
#include <cstdint>

// Problem constants (B=4, S=2048, H=2048, I=1024, E=8, K=2)
#define T_TOKENS 8192
#define H_DIM 2048
#define I_DIM 1024
#define N_EXPERTS 8
#define PAIRS (T_TOKENS * 2)
#define TOT_TILES 144            // sum_b ceil(n_b/128) <= 16384/128 + 16
#define TOT_ROWS (TOT_TILES * 128)

using f32x4 = __attribute__((ext_vector_type(4))) float;
using bfv   = __attribute__((ext_vector_type(8))) short;   // MFMA a/b frag (8 bf16)
using u16x8 = __attribute__((ext_vector_type(8))) unsigned short;

typedef __attribute__((address_space(3))) unsigned int lds_u32;
typedef __attribute__((address_space(1))) unsigned int glb_u32;

__device__ __forceinline__ void gll16(const void* g, void* l) {
  __builtin_amdgcn_global_load_lds((const glb_u32*)g, (lds_u32*)l, 16, 0, 0);
}
#define SB0() __builtin_amdgcn_sched_barrier(0)
#define BAR() __builtin_amdgcn_s_barrier()

__device__ inline unsigned short f2bf(float f) {
  unsigned int u = __float_as_uint(f);
  u += 0x7FFFu + ((u >> 16) & 1u);          // RTN-even
  return (unsigned short)(u >> 16);
}

// ---------------- fp32 -> bf16 bulk convert ----------------
__global__ __launch_bounds__(256) void moe_convert_kernel(
    const float* __restrict__ src, unsigned short* __restrict__ dst, int n8) {
  int i = blockIdx.x * 256 + threadIdx.x;
  if (i >= n8) return;
  size_t o = (size_t)i * 8;
  f32x4 a = *reinterpret_cast<const f32x4*>(src + o);
  f32x4 b = *reinterpret_cast<const f32x4*>(src + o + 4);
  u16x8 r = {f2bf(a[0]), f2bf(a[1]), f2bf(a[2]), f2bf(a[3]),
             f2bf(b[0]), f2bf(b[1]), f2bf(b[2]), f2bf(b[3])};
  *reinterpret_cast<u16x8*>(dst + o) = r;
}

// ---------------- Router: RMSNorm folded into logits, softmax, top-2 (fp32) ----------------
// Also writes the bf16 copy of X (free: X is being read anyway).
__global__ __launch_bounds__(256) void moe_router_kernel(
    const float* __restrict__ X, const float* __restrict__ norm_w,
    const float* __restrict__ rw, float* __restrict__ probs,
    float* __restrict__ topw, int* __restrict__ topi,
    unsigned int* __restrict__ counts, unsigned short* __restrict__ Xb) {
  int t = blockIdx.x;
  int tid = threadIdx.x;
  const float* x = X + (size_t)t * H_DIM;
  int base = tid * 8;
  f32x4 v0 = *reinterpret_cast<const f32x4*>(x + base);
  f32x4 v1 = *reinterpret_cast<const f32x4*>(x + base + 4);
  u16x8 bx = {f2bf(v0[0]), f2bf(v0[1]), f2bf(v0[2]), f2bf(v0[3]),
              f2bf(v1[0]), f2bf(v1[1]), f2bf(v1[2]), f2bf(v1[3])};
  *reinterpret_cast<u16x8*>(Xb + (size_t)t * H_DIM + base) = bx;
  f32x4 nw0 = *reinterpret_cast<const f32x4*>(norm_w + base);
  f32x4 nw1 = *reinterpret_cast<const f32x4*>(norm_w + base + 4);
  float vals[9];
  vals[0] = v0[0]*v0[0] + v0[1]*v0[1] + v0[2]*v0[2] + v0[3]*v0[3]
          + v1[0]*v1[0] + v1[1]*v1[1] + v1[2]*v1[2] + v1[3]*v1[3];
  f32x4 a0 = v0 * nw0, a1 = v1 * nw1;
#pragma unroll
  for (int e = 0; e < 8; ++e) {
    const float* r = rw + e * H_DIM + base;
    f32x4 r0 = *reinterpret_cast<const f32x4*>(r);
    f32x4 r1 = *reinterpret_cast<const f32x4*>(r + 4);
    f32x4 d = a0 * r0 + a1 * r1;
    vals[e + 1] = d[0] + d[1] + d[2] + d[3];
  }
#pragma unroll
  for (int v = 0; v < 9; ++v) {
    float s = vals[v];
#pragma unroll
    for (int off = 32; off > 0; off >>= 1) s += __shfl_xor(s, off);
    vals[v] = s;
  }
  __shared__ float red[4][9];
  int lane = tid & 63, w = tid >> 6;
  if (lane == 0) {
#pragma unroll
    for (int v = 0; v < 9; ++v) red[w][v] = vals[v];
  }
  __syncthreads();
  if (tid == 0) {
    float tot[9];
#pragma unroll
    for (int v = 0; v < 9; ++v) tot[v] = red[0][v] + red[1][v] + red[2][v] + red[3][v];
    float rs = rsqrtf(tot[0] / (float)H_DIM + 1e-6f);
    float lg[8], mx = -1e30f;
#pragma unroll
    for (int e = 0; e < 8; ++e) { lg[e] = tot[e + 1] * rs; mx = fmaxf(mx, lg[e]); }
    float pe[8], sum = 0.f;
#pragma unroll
    for (int e = 0; e < 8; ++e) { pe[e] = expf(lg[e] - mx); sum += pe[e]; }
    float inv = 1.f / sum;
#pragma unroll
    for (int e = 0; e < 8; ++e) { pe[e] *= inv; probs[t * 8 + e] = pe[e]; }
    int b1 = 0; float p1 = pe[0];
#pragma unroll
    for (int e = 1; e < 8; ++e) if (pe[e] > p1) { p1 = pe[e]; b1 = e; }
    int b2 = -1; float p2 = -1.f;
#pragma unroll
    for (int e = 0; e < 8; ++e) if (e != b1 && pe[e] > p2) { p2 = pe[e]; b2 = e; }
    float wsum = p1 + p2;
    topw[t * 2] = p1 / wsum;
    topw[t * 2 + 1] = p2 / wsum;
    topi[t * 2] = b1;
    topi[t * 2 + 1] = b2;
    atomicAdd(&counts[b1], 1u);        // slot-0 bucket
    atomicAdd(&counts[8 + b2], 1u);    // slot-1 bucket
  }
}

// ---------------- importance[e] = sum_t probs[t,e] ----------------
__global__ __launch_bounds__(256) void moe_importance_kernel(
    const float* __restrict__ probs, float* __restrict__ impSum) {
  int e = blockIdx.x, tid = threadIdx.x;
  float s = 0.f;
  for (int t = tid; t < T_TOKENS; t += 256) s += probs[t * 8 + e];
  __shared__ float red[256];
  red[tid] = s;
  __syncthreads();
  for (int st = 128; st > 0; st >>= 1) {
    if (tid < st) red[tid] += red[tid + st];
    __syncthreads();
  }
  if (tid == 0) impSum[e] = red[0];
}

// ---------------- tile offsets + aux loss ----------------
__global__ void moe_offsets_aux_kernel(const unsigned int* __restrict__ counts,
                                       const float* __restrict__ impSum,
                                       int* __restrict__ tileOff,
                                       float* __restrict__ out_aux) {
  if (threadIdx.x == 0 && blockIdx.x == 0) {
    int acc = 0;
    for (int b = 0; b < 16; ++b) {
      tileOff[b] = acc;
      acc += (int)((counts[b] + 127u) >> 7);
    }
    tileOff[16] = acc;
    float a = 0.f;
    for (int e = 0; e < 8; ++e) {
      float load = (float)(counts[e] + counts[8 + e]) / (float)PAIRS;
      a += (impSum[e] / (float)T_TOKENS) * load;
    }
    out_aux[0] = a * (float)N_EXPERTS;
  }
}

// ---------------- bucket pairs (expert x slot) ----------------
__global__ __launch_bounds__(256) void moe_assign_kernel(
    const int* __restrict__ topi, const int* __restrict__ tileOff,
    unsigned int* __restrict__ cursors, int* __restrict__ row2pair) {
  int p = blockIdx.x * 256 + threadIdx.x;
  if (p >= PAIRS) return;
  int b = topi[p] + 8 * (p & 1);
  unsigned int pos = atomicAdd(&cursors[b], 1u);
  row2pair[tileOff[b] * 128 + (int)pos] = p;
}

// ======================= GEMM stages =======================
// Geometry: BM=128 A-rows, 128 B-rows, BK=64, 256 threads = 4 waves.
// Wave w owns B-rows [w*32, w*32+32) x all 128 A-rows: per K-step
// 16 af + 4 bf ds_read_b128 -> 64 MFMA (ratio 0.31; LDS-pipe < MFMA-pipe).
// LDS rows are 128B (64 shorts) with the round-2-proven XOR-8 chunk swizzle:
//   slot(row, c) holds kc = c ^ (row&7); read chunk c = (ks*4+grp) ^ (lane&7).
//   -> any 8 consecutive lanes hit all 8 16B slots: conflict-free (measured 0 in r2).
// gll16: dest linear (wave base + lane*16); source: 8 adjacent lanes read one
// row's full 128B contiguously (kc = (lane&7) ^ (sub&7)) -> fully coalesced.
// Pipeline: prefetch next K-step (8 gll16/thread), s_waitcnt vmcnt(8),
// s_barrier, MFMA cluster (setprio), s_barrier. LDS 64KB dbuf -> 2 blocks/CU.
// Stage A: K-steps = H/64 = 32; nt in [0,16) covers 64 I-cols (gate|up concat).
// Stage B: K-steps = I/64 = 16; nt in [0,16) covers 128 H-cols.

// ---------------- Stage A: P = silu(X@gate^T) * (X@up^T) ----------------
// B-rows per wave: [w*32, w*32+16) = gate, [w*32+16, w*32+32) = up of the SAME
// 16 I-cols -> silu fuse in-register (acc[m][0] = g, acc[m][1] = u).
__global__ __launch_bounds__(256, 2) void moe_stage_a(
    const unsigned short* __restrict__ Xb,
    const unsigned short* __restrict__ Wg, const unsigned short* __restrict__ Wu,
    const int* __restrict__ row2pair, const int* __restrict__ tileOff,
    unsigned int* __restrict__ workCtr, unsigned short* __restrict__ P) {
  __shared__ __align__(16) unsigned short sAB[2][16384];  // A [0,8192) B [8192,16384)
  __shared__ int sTok[128];
  __shared__ int sWork;
  const int tid = threadIdx.x;
  const int lane = tid & 63, w = tid >> 6;
  const int lrow = lane & 15, grp = lane >> 4;
  const int sub = lane >> 3;                 // row within 8-row staging group
  const int kcs = ((lane & 7) ^ sub) << 3;   // source chunk offset (shorts)
  const int cx = (lane & 7) << 3;            // read-side XOR operand (shorts)
  const int nTiles = tileOff[16];
  const int nWork = nTiles * 16;

  for (;;) {
    if (tid == 0) sWork = (int)atomicAdd(workCtr, 1u);
    __syncthreads();
    const int item = sWork;
    if (item >= nWork) break;
    const int mt = item % nTiles;
    const int nt = item / nTiles;       // I-block [nt*64, nt*64+64)
    int b = 0;
#pragma unroll
    for (int k = 1; k < 16; ++k) if (tileOff[k] <= mt) b = k;
    const int e = b & 7;
    const int row0 = mt * 128;
    if (tid < 128) {
      int pr = row2pair[row0 + tid];
      sTok[tid] = (pr >= 0) ? (pr >> 1) : 0;
    }
    __syncthreads();

    const size_t wbase = (size_t)e * ((size_t)I_DIM * H_DIM);
    const unsigned short* src[8];
#pragma unroll
    for (int i = 0; i < 4; ++i) {            // A: row = i*32 + 8w + sub
      int row = i * 32 + 8 * w + sub;
      src[i] = Xb + (size_t)sTok[row] * H_DIM + kcs;
    }
#pragma unroll
    for (int i = 4; i < 8; ++i) {            // B: brow = (i-4)*32 + 8w + sub
      int brow = (i - 4) * 32 + 8 * w + sub;
      int wq = brow >> 5, r5 = brow & 31;
      int ic = nt * 64 + wq * 16 + (r5 & 15);
      const unsigned short* bp = (r5 & 16) ? Wu : Wg;
      src[i] = bp + wbase + (size_t)ic * H_DIM + kcs;
    }

    f32x4 acc[8][2] = {};

#pragma unroll
    for (int i = 0; i < 8; ++i)
      gll16(src[i], (void*)&sAB[0][(i * 256 + tid) * 8]);

    int cur = 0;
#pragma unroll 1
    for (int kk = 0; kk < 32; ++kk) {        // 32 * BK64 = 2048 = H_DIM
      if (kk < 31) {
#pragma unroll
        for (int i = 0; i < 8; ++i)
          gll16(src[i] + ((kk + 1) << 6), (void*)&sAB[cur ^ 1][(i * 256 + tid) * 8]);
        SB0();
        asm volatile("s_waitcnt vmcnt(8)" ::: "memory");
      } else {
        asm volatile("s_waitcnt vmcnt(0)" ::: "memory");
      }
      SB0();
      BAR();
      SB0();
#pragma unroll
      for (int ks = 0; ks < 2; ++ks) {
        const int co = ((ks * 4 + grp) << 3) ^ cx;   // chunk (ks*4+grp)^(lane&7), shorts
        bfv af[8], bf[2];
#pragma unroll
        for (int m = 0; m < 8; ++m)
          af[m] = *reinterpret_cast<const bfv*>(&sAB[cur][(m * 16 + lrow) * 64 + co]);
#pragma unroll
        for (int n = 0; n < 2; ++n)
          bf[n] = *reinterpret_cast<const bfv*>(
              &sAB[cur][8192 + (w * 32 + n * 16 + lrow) * 64 + co]);
        __builtin_amdgcn_s_setprio(1);
#pragma unroll
        for (int m = 0; m < 8; ++m)
#pragma unroll
          for (int n = 0; n < 2; ++n)
            acc[m][n] = __builtin_amdgcn_mfma_f32_16x16x32_bf16(af[m], bf[n], acc[m][n], 0, 0, 0);
        __builtin_amdgcn_s_setprio(0);
      }
      SB0();
      BAR();
      cur ^= 1;
    }

    // epilogue: silu fuse; C/D: row = grp*4+j, col = lrow
#pragma unroll
    for (int m = 0; m < 8; ++m) {
#pragma unroll
      for (int j = 0; j < 4; ++j) {
        float g = acc[m][0][j];
        float uu = acc[m][1][j];
        float pv = (g / (1.f + expf(-g))) * uu;
        int row = row0 + m * 16 + grp * 4 + j;
        int col = nt * 64 + w * 16 + lrow;
        P[(size_t)row * I_DIM + col] = f2bf(pv);
      }
    }
  }
}

// ---------------- Stage B: O = P @ down^T, weighted scatter to out ----------------
// phase 0 (slot-0 buckets): out = 4*w*o ; phase 1 (slot-1): out += 4*w*o.
__global__ __launch_bounds__(256, 2) void moe_stage_b(
    const unsigned short* __restrict__ Pb, const unsigned short* __restrict__ Wd,
    const int* __restrict__ row2pair, const int* __restrict__ tileOff,
    const float* __restrict__ topw, unsigned int* __restrict__ workCtr,
    float* __restrict__ out, int phase) {
  __shared__ __align__(16) unsigned short sAB[2][16384];
  __shared__ int sPair[128];
  __shared__ int sWork;
  const int tid = threadIdx.x;
  const int lane = tid & 63, w = tid >> 6;
  const int lrow = lane & 15, grp = lane >> 4;
  const int sub = lane >> 3;
  const int kcs = ((lane & 7) ^ sub) << 3;
  const int cx = (lane & 7) << 3;
  const int t0 = phase ? tileOff[8] : 0;
  const int t1 = phase ? tileOff[16] : tileOff[8];
  const int nTiles = t1 - t0;
  const int nWork = nTiles * 16;

  for (;;) {
    if (tid == 0) sWork = (int)atomicAdd(workCtr, 1u);
    __syncthreads();
    const int item = sWork;
    if (item >= nWork) break;
    const int mt = t0 + item % nTiles;
    const int nt = item / nTiles;       // H-block [nt*128, nt*128+128)
    int b = 0;
#pragma unroll
    for (int k = 1; k < 16; ++k) if (tileOff[k] <= mt) b = k;
    const int e = b & 7;
    const int row0 = mt * 128, h0 = nt * 128;
    if (tid < 128) sPair[tid] = row2pair[row0 + tid];
    __syncthreads();

    const unsigned short* src[8];
#pragma unroll
    for (int i = 0; i < 4; ++i) {
      int row = i * 32 + 8 * w + sub;
      src[i] = Pb + (size_t)(row0 + row) * I_DIM + kcs;
    }
#pragma unroll
    for (int i = 4; i < 8; ++i) {
      int brow = (i - 4) * 32 + 8 * w + sub;
      src[i] = Wd + (size_t)e * ((size_t)H_DIM * I_DIM) + (size_t)(h0 + brow) * I_DIM + kcs;
    }

    f32x4 acc[8][2] = {};

#pragma unroll
    for (int i = 0; i < 8; ++i)
      gll16(src[i], (void*)&sAB[0][(i * 256 + tid) * 8]);

    int cur = 0;
#pragma unroll 1
    for (int kk = 0; kk < 16; ++kk) {        // 16 * BK64 = 1024 = I_DIM
      if (kk < 15) {
#pragma unroll
        for (int i = 0; i < 8; ++i)
          gll16(src[i] + ((kk + 1) << 6), (void*)&sAB[cur ^ 1][(i * 256 + tid) * 8]);
        SB0();
        asm volatile("s_waitcnt vmcnt(8)" ::: "memory");
      } else {
        asm volatile("s_waitcnt vmcnt(0)" ::: "memory");
      }
      SB0();
      BAR();
      SB0();
#pragma unroll
      for (int ks = 0; ks < 2; ++ks) {
        const int co = ((ks * 4 + grp) << 3) ^ cx;
        bfv af[8], bf[2];
#pragma unroll
        for (int m = 0; m < 8; ++m)
          af[m] = *reinterpret_cast<const bfv*>(&sAB[cur][(m * 16 + lrow) * 64 + co]);
#pragma unroll
        for (int n = 0; n < 2; ++n)
          bf[n] = *reinterpret_cast<const bfv*>(
              &sAB[cur][8192 + (w * 32 + n * 16 + lrow) * 64 + co]);
        __builtin_amdgcn_s_setprio(1);
#pragma unroll
        for (int m = 0; m < 8; ++m)
#pragma unroll
          for (int n = 0; n < 2; ++n)
            acc[m][n] = __builtin_amdgcn_mfma_f32_16x16x32_bf16(af[m], bf[n], acc[m][n], 0, 0, 0);
        __builtin_amdgcn_s_setprio(0);
      }
      SB0();
      BAR();
      cur ^= 1;
    }

#pragma unroll
    for (int m = 0; m < 8; ++m) {
#pragma unroll
      for (int j = 0; j < 4; ++j) {
        int rl = m * 16 + grp * 4 + j;
        int pr = sPair[rl];
        if (pr < 0) continue;
        float wgt = topw[pr] * 4.f;   // SCALING = E/K
        float* orow = out + (size_t)(pr >> 1) * H_DIM + h0 + w * 32 + lrow;
        if (phase) {
#pragma unroll
          for (int n = 0; n < 2; ++n) orow[n * 16] += wgt * acc[m][n][j];
        } else {
#pragma unroll
          for (int n = 0; n < 2; ++n) orow[n * 16] = wgt * acc[m][n][j];
        }
      }
    }
  }
}

// ---------------- launch ----------------
// ws layout (bytes), REQ = 138,879,488 (proven available in round 2):
//   P        @ 0           : 18432*1024*2 = 37,748,736
//   probs    @ 37,748,736  : 262,144
//   topw     @ 38,010,880  : 65,536
//   topi     @ 38,076,416  : 65,536
//   row2pair @ 38,141,952  : 73,728
//   ctrl     @ 38,215,680  : 512  (counts[16] cursors[16] impSum[8] tileOff[17] workCtrs@384)
//   W1       @ 38,216,192  : 33,554,432  (gate bf16; reused for down bf16)
//   W2       @ 71,770,624  : 33,554,432  (up bf16)
//   Xb       @ 105,325,056 : 33,554,432  (X bf16)
extern "C" void kernel_launch(void* const* d_in, const int* in_sizes, int n_in,
                              void* d_out, int out_size, void* d_ws, size_t ws_size,
                              hipStream_t stream) {
  const float* X = (const float*)d_in[0];
  const float* norm_w = (const float*)d_in[1];
  const float* router_w = (const float*)d_in[2];
  const float* gate_w = (const float*)d_in[3];
  const float* up_w = (const float*)d_in[4];
  const float* down_w = (const float*)d_in[5];
  float* out = (float*)d_out;

  char* ws = (char*)d_ws;
  unsigned short* P = (unsigned short*)(ws);
  float* probs = (float*)(ws + 37748736);
  float* topw = (float*)(ws + 38010880);
  int* topi = (int*)(ws + 38076416);
  int* row2pair = (int*)(ws + 38141952);
  char* ctrl = ws + 38215680;
  unsigned int* counts = (unsigned int*)(ctrl);
  unsigned int* cursors = (unsigned int*)(ctrl + 64);
  float* impSum = (float*)(ctrl + 128);
  int* tileOff = (int*)(ctrl + 192);
  unsigned int* wcA = (unsigned int*)(ctrl + 384);
  unsigned int* wcB0 = (unsigned int*)(ctrl + 388);
  unsigned int* wcB1 = (unsigned int*)(ctrl + 392);
  unsigned short* W1 = (unsigned short*)(ws + 38216192);   // gate, then down
  unsigned short* W2 = (unsigned short*)(ws + 71770624);   // up
  unsigned short* Xb = (unsigned short*)(ws + 105325056);

  hipMemsetAsync(ctrl, 0, 512, stream);
  hipMemsetAsync(row2pair, 0xFF, (size_t)TOT_ROWS * 4, stream);

  const int N8 = (N_EXPERTS * I_DIM * H_DIM) / 8;   // 2,097,152
  moe_convert_kernel<<<N8 / 256, 256, 0, stream>>>(gate_w, W1, N8);
  moe_convert_kernel<<<N8 / 256, 256, 0, stream>>>(up_w, W2, N8);

  moe_router_kernel<<<T_TOKENS, 256, 0, stream>>>(X, norm_w, router_w, probs, topw, topi,
                                                  counts, Xb);
  moe_importance_kernel<<<N_EXPERTS, 256, 0, stream>>>(probs, impSum);
  moe_offsets_aux_kernel<<<1, 64, 0, stream>>>(counts, impSum, tileOff, out + 16777216);
  moe_assign_kernel<<<PAIRS / 256, 256, 0, stream>>>(topi, tileOff, cursors, row2pair);

  moe_stage_a<<<512, 256, 0, stream>>>(Xb, W1, W2, row2pair, tileOff, wcA, P);
  moe_convert_kernel<<<N8 / 256, 256, 0, stream>>>(down_w, W1, N8);
  moe_stage_b<<<512, 256, 0, stream>>>(P, W1, row2pair, tileOff, topw, wcB0, out, 0);
  moe_stage_b<<<512, 256, 0, stream>>>(P, W1, row2pair, tileOff, topw, wcB1, out, 1);
}

// Round 11
// 626.391 us; speedup vs baseline: 2.2547x; 1.1426x over previous
//
#include <hip/hip_runtime.h>
#include <hip/hip_bf16.h>
#include <cstdint>

// Problem constants (B=4, S=2048, H=2048, I=1024, E=8, K=2)
#define T_TOKENS 8192
#define H_DIM 2048
#define I_DIM 1024
#define N_EXPERTS 8
#define PAIRS (T_TOKENS * 2)
#define TOT_TILES 144            // sum_b ceil(n_b/128) <= 16384/128 + 16
#define TOT_ROWS (TOT_TILES * 128)

using f32x4 = __attribute__((ext_vector_type(4))) float;
using bfv   = __attribute__((ext_vector_type(8))) short;   // MFMA a/b frag (8 bf16)
using u16x8 = __attribute__((ext_vector_type(8))) unsigned short;

typedef __attribute__((address_space(3))) unsigned int lds_u32;
typedef __attribute__((address_space(1))) unsigned int glb_u32;

// async global->LDS, 16B/lane, OFFSET ALWAYS 0 (non-zero imm caused r10 fault)
__device__ __forceinline__ void gll16(const void* g, void* l) {
  __builtin_amdgcn_global_load_lds((const glb_u32*)g, (lds_u32*)l, 16, 0, 0);
}
#define SB0() __builtin_amdgcn_sched_barrier(0)
#define BAR() __builtin_amdgcn_s_barrier()

__device__ inline unsigned short f2bf(float f) {
  unsigned int u = __float_as_uint(f);
  u += 0x7FFFu + ((u >> 16) & 1u);          // RTN-even
  return (unsigned short)(u >> 16);
}
__device__ inline float bf2f(unsigned short u) {
  return __uint_as_float((unsigned int)u << 16);
}

// ---------------- fp32 -> bf16 bulk convert (fallback for down_w) ----------------
__global__ __launch_bounds__(256) void moe_convert_kernel(
    const float* __restrict__ src, unsigned short* __restrict__ dst, int n8) {
  int i = blockIdx.x * 256 + threadIdx.x;
  if (i >= n8) return;
  size_t o = (size_t)i * 8;
  f32x4 a = *reinterpret_cast<const f32x4*>(src + o);
  f32x4 b = *reinterpret_cast<const f32x4*>(src + o + 4);
  u16x8 r = {f2bf(a[0]), f2bf(a[1]), f2bf(a[2]), f2bf(a[3]),
             f2bf(b[0]), f2bf(b[1]), f2bf(b[2]), f2bf(b[3])};
  *reinterpret_cast<u16x8*>(dst + o) = r;
}

// ---------------- Router: RMSNorm->logits->softmax->top-2 (fp32) ----------------
// Fused: bf16 copy of X, bf16 conversion of gate/up (+down if W3 non-null).
__global__ __launch_bounds__(256) void moe_router_kernel(
    const float* __restrict__ X, const float* __restrict__ norm_w,
    const float* __restrict__ rw, float* __restrict__ probs,
    float* __restrict__ topw, int* __restrict__ topi,
    unsigned int* __restrict__ counts, unsigned short* __restrict__ Xb,
    const float* __restrict__ gate_w, const float* __restrict__ up_w,
    const float* __restrict__ down_w,
    unsigned short* __restrict__ W1, unsigned short* __restrict__ W2,
    unsigned short* __restrict__ W3) {
  int t = blockIdx.x;
  int tid = threadIdx.x;
  {  // fused weight-convert slice: 2048 floats per block per tensor
    size_t co = (size_t)t * 2048 + tid * 8;
    f32x4 a = *reinterpret_cast<const f32x4*>(gate_w + co);
    f32x4 b = *reinterpret_cast<const f32x4*>(gate_w + co + 4);
    u16x8 r = {f2bf(a[0]), f2bf(a[1]), f2bf(a[2]), f2bf(a[3]),
               f2bf(b[0]), f2bf(b[1]), f2bf(b[2]), f2bf(b[3])};
    *reinterpret_cast<u16x8*>(W1 + co) = r;
    a = *reinterpret_cast<const f32x4*>(up_w + co);
    b = *reinterpret_cast<const f32x4*>(up_w + co + 4);
    u16x8 r2 = {f2bf(a[0]), f2bf(a[1]), f2bf(a[2]), f2bf(a[3]),
                f2bf(b[0]), f2bf(b[1]), f2bf(b[2]), f2bf(b[3])};
    *reinterpret_cast<u16x8*>(W2 + co) = r2;
    if (W3) {
      a = *reinterpret_cast<const f32x4*>(down_w + co);
      b = *reinterpret_cast<const f32x4*>(down_w + co + 4);
      u16x8 r3 = {f2bf(a[0]), f2bf(a[1]), f2bf(a[2]), f2bf(a[3]),
                  f2bf(b[0]), f2bf(b[1]), f2bf(b[2]), f2bf(b[3])};
      *reinterpret_cast<u16x8*>(W3 + co) = r3;
    }
  }
  const float* x = X + (size_t)t * H_DIM;
  int base = tid * 8;
  f32x4 v0 = *reinterpret_cast<const f32x4*>(x + base);
  f32x4 v1 = *reinterpret_cast<const f32x4*>(x + base + 4);
  u16x8 bx = {f2bf(v0[0]), f2bf(v0[1]), f2bf(v0[2]), f2bf(v0[3]),
              f2bf(v1[0]), f2bf(v1[1]), f2bf(v1[2]), f2bf(v1[3])};
  *reinterpret_cast<u16x8*>(Xb + (size_t)t * H_DIM + base) = bx;
  f32x4 nw0 = *reinterpret_cast<const f32x4*>(norm_w + base);
  f32x4 nw1 = *reinterpret_cast<const f32x4*>(norm_w + base + 4);
  float vals[9];
  vals[0] = v0[0]*v0[0] + v0[1]*v0[1] + v0[2]*v0[2] + v0[3]*v0[3]
          + v1[0]*v1[0] + v1[1]*v1[1] + v1[2]*v1[2] + v1[3]*v1[3];
  f32x4 a0 = v0 * nw0, a1 = v1 * nw1;
#pragma unroll
  for (int e = 0; e < 8; ++e) {
    const float* r = rw + e * H_DIM + base;
    f32x4 r0 = *reinterpret_cast<const f32x4*>(r);
    f32x4 r1 = *reinterpret_cast<const f32x4*>(r + 4);
    f32x4 d = a0 * r0 + a1 * r1;
    vals[e + 1] = d[0] + d[1] + d[2] + d[3];
  }
#pragma unroll
  for (int v = 0; v < 9; ++v) {
    float s = vals[v];
#pragma unroll
    for (int off = 32; off > 0; off >>= 1) s += __shfl_xor(s, off);
    vals[v] = s;
  }
  __shared__ float red[4][9];
  int lane = tid & 63, w = tid >> 6;
  if (lane == 0) {
#pragma unroll
    for (int v = 0; v < 9; ++v) red[w][v] = vals[v];
  }
  __syncthreads();
  if (tid == 0) {
    float tot[9];
#pragma unroll
    for (int v = 0; v < 9; ++v) tot[v] = red[0][v] + red[1][v] + red[2][v] + red[3][v];
    float rs = rsqrtf(tot[0] / (float)H_DIM + 1e-6f);
    float lg[8], mx = -1e30f;
#pragma unroll
    for (int e = 0; e < 8; ++e) { lg[e] = tot[e + 1] * rs; mx = fmaxf(mx, lg[e]); }
    float pe[8], sum = 0.f;
#pragma unroll
    for (int e = 0; e < 8; ++e) { pe[e] = expf(lg[e] - mx); sum += pe[e]; }
    float inv = 1.f / sum;
#pragma unroll
    for (int e = 0; e < 8; ++e) { pe[e] *= inv; probs[t * 8 + e] = pe[e]; }
    int b1 = 0; float p1 = pe[0];
#pragma unroll
    for (int e = 1; e < 8; ++e) if (pe[e] > p1) { p1 = pe[e]; b1 = e; }
    int b2 = -1; float p2 = -1.f;
#pragma unroll
    for (int e = 0; e < 8; ++e) if (e != b1 && pe[e] > p2) { p2 = pe[e]; b2 = e; }
    float wsum = p1 + p2;
    topw[t * 2] = p1 / wsum;
    topw[t * 2 + 1] = p2 / wsum;
    topi[t * 2] = b1;
    topi[t * 2 + 1] = b2;
    atomicAdd(&counts[b1], 1u);        // slot-0 bucket
    atomicAdd(&counts[8 + b2], 1u);    // slot-1 bucket
  }
}

// ---------------- importance[e] = sum_t probs[t,e] ----------------
__global__ __launch_bounds__(256) void moe_importance_kernel(
    const float* __restrict__ probs, float* __restrict__ impSum) {
  int e = blockIdx.x, tid = threadIdx.x;
  float s = 0.f;
  for (int t = tid; t < T_TOKENS; t += 256) s += probs[t * 8 + e];
  __shared__ float red[256];
  red[tid] = s;
  __syncthreads();
  for (int st = 128; st > 0; st >>= 1) {
    if (tid < st) red[tid] += red[tid + st];
    __syncthreads();
  }
  if (tid == 0) impSum[e] = red[0];
}

// ---------------- tile offsets + aux loss ----------------
__global__ void moe_offsets_aux_kernel(const unsigned int* __restrict__ counts,
                                       const float* __restrict__ impSum,
                                       int* __restrict__ tileOff,
                                       float* __restrict__ out_aux) {
  if (threadIdx.x == 0 && blockIdx.x == 0) {
    int acc = 0;
    for (int b = 0; b < 16; ++b) {
      tileOff[b] = acc;
      acc += (int)((counts[b] + 127u) >> 7);
    }
    tileOff[16] = acc;
    float a = 0.f;
    for (int e = 0; e < 8; ++e) {
      float load = (float)(counts[e] + counts[8 + e]) / (float)PAIRS;
      a += (impSum[e] / (float)T_TOKENS) * load;
    }
    out_aux[0] = a * (float)N_EXPERTS;
  }
}

// ---------------- bucket pairs (expert x slot) ----------------
__global__ __launch_bounds__(256) void moe_assign_kernel(
    const int* __restrict__ topi, const int* __restrict__ tileOff,
    unsigned int* __restrict__ cursors, int* __restrict__ row2pair) {
  int p = blockIdx.x * 256 + threadIdx.x;
  if (p >= PAIRS) return;
  int b = topi[p] + 8 * (p & 1);
  unsigned int pos = atomicAdd(&cursors[b], 1u);
  row2pair[tileOff[b] * 128 + (int)pos] = p;
}

// ======================= GEMM stages =======================
// BM=128 A-rows, BN=128 B-rows, BK=64, 4 waves in 2M x 2N (wave tile 64x64):
// per K-step per wave: 2 ks x (4 af + 4 bf) ds_read_b128 -> 32 MFMA (ratio 0.5).
// LDS rows = 128B, XOR-8 chunk swizzle (0-conflict, proven r2/r9):
//   slot(row,kc) = kc ^ (row&7); read slot = (ks*4+grp) ^ (lane&7).
// gll16: dest linear (base+lane*16), offset imm 0; 8 adjacent lanes read one
// row's 128B contiguously (src chunk = (lane&7)^sub) -> fully coalesced.
// Pipeline (r9-proven): prefetch next K-step (8 gll16), s_waitcnt vmcnt(8),
// barrier, 2x{8 ds_read + 16 MFMA (setprio)}, barrier. 64KB dbuf -> 2 blk/CU.
// Stage A: NK = H/64 = 32.  Stage B: NK = I/64 = 16.

// ---------------- Stage A: P = silu(X@gate^T) * (X@up^T) ----------------
// BN=128 B-rows = 64 I-cols as gate|up: B-row (wq=brow>>6, r6=brow&63) is
// gate (r6<32) or up (r6>=32) of I-col nt*64 + wq*32 + (r6&31).
// Wave wn reads rows wn*64+n*16+lrow: n<2 gate, n>=2 up of the SAME col ->
// silu fuse in-register: acc[m][n] gate, acc[m][n+2] up.
__global__ __launch_bounds__(256, 2) void moe_stage_a(
    const unsigned short* __restrict__ Xb,
    const unsigned short* __restrict__ Wg, const unsigned short* __restrict__ Wu,
    const int* __restrict__ row2pair, const int* __restrict__ tileOff,
    unsigned int* __restrict__ workCtr, unsigned short* __restrict__ P) {
  __shared__ __align__(16) unsigned short sAB[2][16384];  // A [0,8192) B [8192,16384)
  __shared__ int sTok[128];
  __shared__ int sWork;
  const int tid = threadIdx.x;
  const int lane = tid & 63, w = tid >> 6;
  const int wm = w >> 1, wn = w & 1;
  const int lrow = lane & 15, grp = lane >> 4;
  const int sub = lane >> 3;
  const int kcs = ((lane & 7) ^ sub) << 3;   // src chunk offset (shorts)
  const int cx = (lane & 7) << 3;            // read-side XOR operand (shorts)
  const int nTiles = tileOff[16];
  const int nWork = nTiles * 16;

  for (;;) {
    if (tid == 0) sWork = (int)atomicAdd(workCtr, 1u);
    __syncthreads();
    const int item = sWork;
    if (item >= nWork) break;
    const int mt = item % nTiles;
    const int nt = item / nTiles;       // I-block [nt*64, nt*64+64)
    int b = 0;
#pragma unroll
    for (int k = 1; k < 16; ++k) if (tileOff[k] <= mt) b = k;
    const int e = b & 7;
    const int row0 = mt * 128;
    if (tid < 128) {
      int pr = row2pair[row0 + tid];
      sTok[tid] = (pr >= 0) ? (pr >> 1) : 0;
    }
    __syncthreads();

    const size_t wbase = (size_t)e * ((size_t)I_DIM * H_DIM);
    const unsigned short* src[8];
#pragma unroll
    for (int i = 0; i < 4; ++i) {            // A: row = i*32 + 8w + sub
      int row = i * 32 + 8 * w + sub;
      src[i] = Xb + (size_t)sTok[row] * H_DIM + kcs;
    }
#pragma unroll
    for (int i = 4; i < 8; ++i) {            // B: brow = (i-4)*32 + 8w + sub
      int brow = (i - 4) * 32 + 8 * w + sub;
      int wq = brow >> 6, r6 = brow & 63;
      int ic = nt * 64 + wq * 32 + (r6 & 31);
      const unsigned short* bp = (r6 & 32) ? Wu : Wg;
      src[i] = bp + wbase + (size_t)ic * H_DIM + kcs;
    }

    f32x4 acc[4][4] = {};

#pragma unroll
    for (int i = 0; i < 8; ++i)
      gll16(src[i], (void*)&sAB[0][(i * 256 + tid) * 8]);

    int cur = 0;
#pragma unroll 1
    for (int kk = 0; kk < 32; ++kk) {        // 32 * BK64 = 2048 = H_DIM
      if (kk < 31) {
#pragma unroll
        for (int i = 0; i < 8; ++i)
          gll16(src[i] + ((kk + 1) << 6), (void*)&sAB[cur ^ 1][(i * 256 + tid) * 8]);
        SB0();
        asm volatile("s_waitcnt vmcnt(8)" ::: "memory");
      } else {
        asm volatile("s_waitcnt vmcnt(0)" ::: "memory");
      }
      SB0();
      BAR();
      SB0();
#pragma unroll
      for (int ks = 0; ks < 2; ++ks) {
        const int co = ((ks * 4 + grp) << 3) ^ cx;
        bfv af[4], bf[4];
#pragma unroll
        for (int m = 0; m < 4; ++m)
          af[m] = *reinterpret_cast<const bfv*>(
              &sAB[cur][(wm * 64 + m * 16 + lrow) * 64 + co]);
#pragma unroll
        for (int n = 0; n < 4; ++n)
          bf[n] = *reinterpret_cast<const bfv*>(
              &sAB[cur][8192 + (wn * 64 + n * 16 + lrow) * 64 + co]);
        __builtin_amdgcn_s_setprio(1);
#pragma unroll
        for (int m = 0; m < 4; ++m)
#pragma unroll
          for (int n = 0; n < 4; ++n)
            acc[m][n] = __builtin_amdgcn_mfma_f32_16x16x32_bf16(af[m], bf[n], acc[m][n], 0, 0, 0);
        __builtin_amdgcn_s_setprio(0);
      }
      SB0();
      BAR();
      cur ^= 1;
    }

    // epilogue: silu fuse; C/D: row = grp*4+j, col = lrow
#pragma unroll
    for (int m = 0; m < 4; ++m) {
#pragma unroll
      for (int n = 0; n < 2; ++n) {
#pragma unroll
        for (int j = 0; j < 4; ++j) {
          float g = acc[m][n][j];
          float uu = acc[m][n + 2][j];
          float pv = (g / (1.f + expf(-g))) * uu;
          int row = row0 + wm * 64 + m * 16 + grp * 4 + j;
          int col = nt * 64 + wn * 32 + n * 16 + lrow;
          P[(size_t)row * I_DIM + col] = f2bf(pv);
        }
      }
    }
  }
}

// ---------------- Stage B (one-shot): O = P @ down^T -> Opairs (bf16) ----------------
__global__ __launch_bounds__(256, 2) void moe_stage_b(
    const unsigned short* __restrict__ Pb, const unsigned short* __restrict__ Wd,
    const int* __restrict__ row2pair, const int* __restrict__ tileOff,
    unsigned int* __restrict__ workCtr, unsigned short* __restrict__ Opairs) {
  __shared__ __align__(16) unsigned short sAB[2][16384];
  __shared__ int sPair[128];
  __shared__ int sWork;
  const int tid = threadIdx.x;
  const int lane = tid & 63, w = tid >> 6;
  const int wm = w >> 1, wn = w & 1;
  const int lrow = lane & 15, grp = lane >> 4;
  const int sub = lane >> 3;
  const int kcs = ((lane & 7) ^ sub) << 3;
  const int cx = (lane & 7) << 3;
  const int nTiles = tileOff[16];
  const int nWork = nTiles * 16;

  for (;;) {
    if (tid == 0) sWork = (int)atomicAdd(workCtr, 1u);
    __syncthreads();
    const int item = sWork;
    if (item >= nWork) break;
    const int mt = item % nTiles;
    const int nt = item / nTiles;       // H-block [nt*128, nt*128+128)
    int b = 0;
#pragma unroll
    for (int k = 1; k < 16; ++k) if (tileOff[k] <= mt) b = k;
    const int e = b & 7;
    const int row0 = mt * 128, h0 = nt * 128;
    if (tid < 128) sPair[tid] = row2pair[row0 + tid];
    __syncthreads();

    const unsigned short* src[8];
#pragma unroll
    for (int i = 0; i < 4; ++i) {
      int row = i * 32 + 8 * w + sub;
      src[i] = Pb + (size_t)(row0 + row) * I_DIM + kcs;
    }
#pragma unroll
    for (int i = 4; i < 8; ++i) {
      int brow = (i - 4) * 32 + 8 * w + sub;
      src[i] = Wd + (size_t)e * ((size_t)H_DIM * I_DIM) + (size_t)(h0 + brow) * I_DIM + kcs;
    }

    f32x4 acc[4][4] = {};

#pragma unroll
    for (int i = 0; i < 8; ++i)
      gll16(src[i], (void*)&sAB[0][(i * 256 + tid) * 8]);

    int cur = 0;
#pragma unroll 1
    for (int kk = 0; kk < 16; ++kk) {        // 16 * BK64 = 1024 = I_DIM
      if (kk < 15) {
#pragma unroll
        for (int i = 0; i < 8; ++i)
          gll16(src[i] + ((kk + 1) << 6), (void*)&sAB[cur ^ 1][(i * 256 + tid) * 8]);
        SB0();
        asm volatile("s_waitcnt vmcnt(8)" ::: "memory");
      } else {
        asm volatile("s_waitcnt vmcnt(0)" ::: "memory");
      }
      SB0();
      BAR();
      SB0();
#pragma unroll
      for (int ks = 0; ks < 2; ++ks) {
        const int co = ((ks * 4 + grp) << 3) ^ cx;
        bfv af[4], bf[4];
#pragma unroll
        for (int m = 0; m < 4; ++m)
          af[m] = *reinterpret_cast<const bfv*>(
              &sAB[cur][(wm * 64 + m * 16 + lrow) * 64 + co]);
#pragma unroll
        for (int n = 0; n < 4; ++n)
          bf[n] = *reinterpret_cast<const bfv*>(
              &sAB[cur][8192 + (wn * 64 + n * 16 + lrow) * 64 + co]);
        __builtin_amdgcn_s_setprio(1);
#pragma unroll
        for (int m = 0; m < 4; ++m)
#pragma unroll
          for (int n = 0; n < 4; ++n)
            acc[m][n] = __builtin_amdgcn_mfma_f32_16x16x32_bf16(af[m], bf[n], acc[m][n], 0, 0, 0);
        __builtin_amdgcn_s_setprio(0);
      }
      SB0();
      BAR();
      cur ^= 1;
    }

#pragma unroll
    for (int m = 0; m < 4; ++m) {
#pragma unroll
      for (int j = 0; j < 4; ++j) {
        int rl = wm * 64 + m * 16 + grp * 4 + j;
        int pr = sPair[rl];
        if (pr < 0) continue;
        unsigned short* orow = Opairs + (size_t)pr * H_DIM + h0 + wn * 64 + lrow;
#pragma unroll
        for (int n = 0; n < 4; ++n) orow[n * 16] = f2bf(acc[m][n][j]);
      }
    }
  }
}

// ---------------- Combine: out[t] = 4 * (w0*O[2t] + w1*O[2t+1]) ----------------
__global__ __launch_bounds__(256) void moe_combine_kernel(
    const unsigned short* __restrict__ Opairs, const float* __restrict__ topw,
    float* __restrict__ out) {
  size_t g = (size_t)blockIdx.x * 256 + threadIdx.x;
  size_t base = g * 8;
  int t = (int)(base >> 11);
  int h = (int)(base & 2047);
  float w0 = topw[t * 2] * 4.f;
  float w1 = topw[t * 2 + 1] * 4.f;
  u16x8 o0 = *reinterpret_cast<const u16x8*>(Opairs + (size_t)(t * 2) * H_DIM + h);
  u16x8 o1 = *reinterpret_cast<const u16x8*>(Opairs + (size_t)(t * 2 + 1) * H_DIM + h);
  f32x4 r0, r1;
#pragma unroll
  for (int j = 0; j < 4; ++j) r0[j] = w0 * bf2f(o0[j]) + w1 * bf2f(o1[j]);
#pragma unroll
  for (int j = 0; j < 4; ++j) r1[j] = w0 * bf2f(o0[4 + j]) + w1 * bf2f(o1[4 + j]);
  *reinterpret_cast<f32x4*>(out + base) = r0;
  *reinterpret_cast<f32x4*>(out + base + 4) = r1;
}

// ---------------- launch ----------------
// ws layout (bytes), REQ = 138,879,488 (proven); REQ3 = 172,433,920 (gated):
//   P        @ 0           : 18432*1024*2 = 37,748,736
//   probs    @ 37,748,736  : 262,144
//   topw     @ 38,010,880  : 65,536
//   topi     @ 38,076,416  : 65,536
//   row2pair @ 38,141,952  : 73,728
//   ctrl     @ 38,215,680  : 512
//   W1       @ 38,216,192  : 33,554,432  (gate bf16; down bf16 in fallback)
//   W2       @ 71,770,624  : 33,554,432  (up bf16)
//   Xb       @ 105,325,056 : 33,554,432  (X bf16)
//   Opairs   @ 71,770,624  : 67,108,864  (overlays W2+Xb; both dead in stage B)
//   W3       @ 138,879,488 : 33,554,432  (down bf16, only if ws_size >= REQ3)
extern "C" void kernel_launch(void* const* d_in, const int* in_sizes, int n_in,
                              void* d_out, int out_size, void* d_ws, size_t ws_size,
                              hipStream_t stream) {
  const float* X = (const float*)d_in[0];
  const float* norm_w = (const float*)d_in[1];
  const float* router_w = (const float*)d_in[2];
  const float* gate_w = (const float*)d_in[3];
  const float* up_w = (const float*)d_in[4];
  const float* down_w = (const float*)d_in[5];
  float* out = (float*)d_out;

  char* ws = (char*)d_ws;
  unsigned short* P = (unsigned short*)(ws);
  float* probs = (float*)(ws + 37748736);
  float* topw = (float*)(ws + 38010880);
  int* topi = (int*)(ws + 38076416);
  int* row2pair = (int*)(ws + 38141952);
  char* ctrl = ws + 38215680;
  unsigned int* counts = (unsigned int*)(ctrl);
  unsigned int* cursors = (unsigned int*)(ctrl + 64);
  float* impSum = (float*)(ctrl + 128);
  int* tileOff = (int*)(ctrl + 192);
  unsigned int* wcA = (unsigned int*)(ctrl + 384);
  unsigned int* wcB = (unsigned int*)(ctrl + 388);
  unsigned short* W1 = (unsigned short*)(ws + 38216192);
  unsigned short* W2 = (unsigned short*)(ws + 71770624);
  unsigned short* Xb = (unsigned short*)(ws + 105325056);
  unsigned short* Opairs = (unsigned short*)(ws + 71770624);
  unsigned short* W3 = (unsigned short*)(ws + 138879488);
  const bool w3ok = ws_size >= 172433920ull;

  hipMemsetAsync(ctrl, 0, 512, stream);
  hipMemsetAsync(row2pair, 0xFF, (size_t)TOT_ROWS * 4, stream);

  moe_router_kernel<<<T_TOKENS, 256, 0, stream>>>(
      X, norm_w, router_w, probs, topw, topi, counts, Xb,
      gate_w, up_w, down_w, W1, W2, w3ok ? W3 : nullptr);
  moe_importance_kernel<<<N_EXPERTS, 256, 0, stream>>>(probs, impSum);
  moe_offsets_aux_kernel<<<1, 64, 0, stream>>>(counts, impSum, tileOff, out + 16777216);
  moe_assign_kernel<<<PAIRS / 256, 256, 0, stream>>>(topi, tileOff, cursors, row2pair);

  moe_stage_a<<<512, 256, 0, stream>>>(Xb, W1, W2, row2pair, tileOff, wcA, P);

  const unsigned short* DW = W3;
  if (!w3ok) {
    const int N8 = (N_EXPERTS * I_DIM * H_DIM) / 8;   // 2,097,152
    moe_convert_kernel<<<N8 / 256, 256, 0, stream>>>(down_w, W1, N8);  // gate dead
    DW = W1;
  }
  moe_stage_b<<<512, 256, 0, stream>>>(P, DW, row2pair, tileOff, wcB, Opairs);
  moe_combine_kernel<<<T_TOKENS, 256, 0, stream>>>(Opairs, topw, out);
}

// Round 12
// 623.190 us; speedup vs baseline: 2.2662x; 1.0051x over previous
//
#include <hip/hip_runtime.h>
#include <hip/hip_bf16.h>
#include <cstdint>

// Problem constants (B=4, S=2048, H=2048, I=1024, E=8, K=2)
#define T_TOKENS 8192
#define H_DIM 2048
#define I_DIM 1024
#define N_EXPERTS 8
#define PAIRS (T_TOKENS * 2)
#define TOT_TILES 144            // sum_b ceil(n_b/128) <= 16384/128 + 16
#define TOT_ROWS (TOT_TILES * 128)

using f32x4 = __attribute__((ext_vector_type(4))) float;
using bfv   = __attribute__((ext_vector_type(8))) short;   // MFMA a/b frag (8 bf16)
using u16x8 = __attribute__((ext_vector_type(8))) unsigned short;

typedef __attribute__((address_space(3))) unsigned int lds_u32;
typedef __attribute__((address_space(1))) unsigned int glb_u32;

// async global->LDS, 16B/lane, OFFSET ALWAYS 0 (non-zero imm faulted in r10)
__device__ __forceinline__ void gll16(const void* g, void* l) {
  __builtin_amdgcn_global_load_lds((const glb_u32*)g, (lds_u32*)l, 16, 0, 0);
}
#define SB0() __builtin_amdgcn_sched_barrier(0)
#define BAR() __builtin_amdgcn_s_barrier()

__device__ inline unsigned short f2bf(float f) {
  unsigned int u = __float_as_uint(f);
  u += 0x7FFFu + ((u >> 16) & 1u);          // RTN-even
  return (unsigned short)(u >> 16);
}
__device__ inline float bf2f(unsigned short u) {
  return __uint_as_float((unsigned int)u << 16);
}

// ---------------- fp32 -> bf16 bulk convert (fallback for down_w) ----------------
__global__ __launch_bounds__(256) void moe_convert_kernel(
    const float* __restrict__ src, unsigned short* __restrict__ dst, int n8) {
  int i = blockIdx.x * 256 + threadIdx.x;
  if (i >= n8) return;
  size_t o = (size_t)i * 8;
  f32x4 a = *reinterpret_cast<const f32x4*>(src + o);
  f32x4 b = *reinterpret_cast<const f32x4*>(src + o + 4);
  u16x8 r = {f2bf(a[0]), f2bf(a[1]), f2bf(a[2]), f2bf(a[3]),
             f2bf(b[0]), f2bf(b[1]), f2bf(b[2]), f2bf(b[3])};
  *reinterpret_cast<u16x8*>(dst + o) = r;
}

// ---------------- Router: RMSNorm->logits->softmax->top-2 (fp32) ----------------
// Fused: bf16 copy of X, bf16 conversion of gate/up (+down if W3 non-null).
__global__ __launch_bounds__(256) void moe_router_kernel(
    const float* __restrict__ X, const float* __restrict__ norm_w,
    const float* __restrict__ rw, float* __restrict__ probs,
    float* __restrict__ topw, int* __restrict__ topi,
    unsigned int* __restrict__ counts, unsigned short* __restrict__ Xb,
    const float* __restrict__ gate_w, const float* __restrict__ up_w,
    const float* __restrict__ down_w,
    unsigned short* __restrict__ W1, unsigned short* __restrict__ W2,
    unsigned short* __restrict__ W3) {
  int t = blockIdx.x;
  int tid = threadIdx.x;
  {  // fused weight-convert slice: 2048 floats per block per tensor
    size_t co = (size_t)t * 2048 + tid * 8;
    f32x4 a = *reinterpret_cast<const f32x4*>(gate_w + co);
    f32x4 b = *reinterpret_cast<const f32x4*>(gate_w + co + 4);
    u16x8 r = {f2bf(a[0]), f2bf(a[1]), f2bf(a[2]), f2bf(a[3]),
               f2bf(b[0]), f2bf(b[1]), f2bf(b[2]), f2bf(b[3])};
    *reinterpret_cast<u16x8*>(W1 + co) = r;
    a = *reinterpret_cast<const f32x4*>(up_w + co);
    b = *reinterpret_cast<const f32x4*>(up_w + co + 4);
    u16x8 r2 = {f2bf(a[0]), f2bf(a[1]), f2bf(a[2]), f2bf(a[3]),
                f2bf(b[0]), f2bf(b[1]), f2bf(b[2]), f2bf(b[3])};
    *reinterpret_cast<u16x8*>(W2 + co) = r2;
    if (W3) {
      a = *reinterpret_cast<const f32x4*>(down_w + co);
      b = *reinterpret_cast<const f32x4*>(down_w + co + 4);
      u16x8 r3 = {f2bf(a[0]), f2bf(a[1]), f2bf(a[2]), f2bf(a[3]),
                  f2bf(b[0]), f2bf(b[1]), f2bf(b[2]), f2bf(b[3])};
      *reinterpret_cast<u16x8*>(W3 + co) = r3;
    }
  }
  const float* x = X + (size_t)t * H_DIM;
  int base = tid * 8;
  f32x4 v0 = *reinterpret_cast<const f32x4*>(x + base);
  f32x4 v1 = *reinterpret_cast<const f32x4*>(x + base + 4);
  u16x8 bx = {f2bf(v0[0]), f2bf(v0[1]), f2bf(v0[2]), f2bf(v0[3]),
              f2bf(v1[0]), f2bf(v1[1]), f2bf(v1[2]), f2bf(v1[3])};
  *reinterpret_cast<u16x8*>(Xb + (size_t)t * H_DIM + base) = bx;
  f32x4 nw0 = *reinterpret_cast<const f32x4*>(norm_w + base);
  f32x4 nw1 = *reinterpret_cast<const f32x4*>(norm_w + base + 4);
  float vals[9];
  vals[0] = v0[0]*v0[0] + v0[1]*v0[1] + v0[2]*v0[2] + v0[3]*v0[3]
          + v1[0]*v1[0] + v1[1]*v1[1] + v1[2]*v1[2] + v1[3]*v1[3];
  f32x4 a0 = v0 * nw0, a1 = v1 * nw1;
#pragma unroll
  for (int e = 0; e < 8; ++e) {
    const float* r = rw + e * H_DIM + base;
    f32x4 r0 = *reinterpret_cast<const f32x4*>(r);
    f32x4 r1 = *reinterpret_cast<const f32x4*>(r + 4);
    f32x4 d = a0 * r0 + a1 * r1;
    vals[e + 1] = d[0] + d[1] + d[2] + d[3];
  }
#pragma unroll
  for (int v = 0; v < 9; ++v) {
    float s = vals[v];
#pragma unroll
    for (int off = 32; off > 0; off >>= 1) s += __shfl_xor(s, off);
    vals[v] = s;
  }
  __shared__ float red[4][9];
  int lane = tid & 63, w = tid >> 6;
  if (lane == 0) {
#pragma unroll
    for (int v = 0; v < 9; ++v) red[w][v] = vals[v];
  }
  __syncthreads();
  if (tid == 0) {
    float tot[9];
#pragma unroll
    for (int v = 0; v < 9; ++v) tot[v] = red[0][v] + red[1][v] + red[2][v] + red[3][v];
    float rs = rsqrtf(tot[0] / (float)H_DIM + 1e-6f);
    float lg[8], mx = -1e30f;
#pragma unroll
    for (int e = 0; e < 8; ++e) { lg[e] = tot[e + 1] * rs; mx = fmaxf(mx, lg[e]); }
    float pe[8], sum = 0.f;
#pragma unroll
    for (int e = 0; e < 8; ++e) { pe[e] = expf(lg[e] - mx); sum += pe[e]; }
    float inv = 1.f / sum;
#pragma unroll
    for (int e = 0; e < 8; ++e) { pe[e] *= inv; probs[t * 8 + e] = pe[e]; }
    int b1 = 0; float p1 = pe[0];
#pragma unroll
    for (int e = 1; e < 8; ++e) if (pe[e] > p1) { p1 = pe[e]; b1 = e; }
    int b2 = -1; float p2 = -1.f;
#pragma unroll
    for (int e = 0; e < 8; ++e) if (e != b1 && pe[e] > p2) { p2 = pe[e]; b2 = e; }
    float wsum = p1 + p2;
    topw[t * 2] = p1 / wsum;
    topw[t * 2 + 1] = p2 / wsum;
    topi[t * 2] = b1;
    topi[t * 2 + 1] = b2;
    atomicAdd(&counts[b1], 1u);        // slot-0 bucket
    atomicAdd(&counts[8 + b2], 1u);    // slot-1 bucket
  }
}

// ---------------- importance[e] = sum_t probs[t,e] ----------------
__global__ __launch_bounds__(256) void moe_importance_kernel(
    const float* __restrict__ probs, float* __restrict__ impSum) {
  int e = blockIdx.x, tid = threadIdx.x;
  float s = 0.f;
  for (int t = tid; t < T_TOKENS; t += 256) s += probs[t * 8 + e];
  __shared__ float red[256];
  red[tid] = s;
  __syncthreads();
  for (int st = 128; st > 0; st >>= 1) {
    if (tid < st) red[tid] += red[tid + st];
    __syncthreads();
  }
  if (tid == 0) impSum[e] = red[0];
}

// ---------------- tile offsets + aux loss ----------------
__global__ void moe_offsets_aux_kernel(const unsigned int* __restrict__ counts,
                                       const float* __restrict__ impSum,
                                       int* __restrict__ tileOff,
                                       float* __restrict__ out_aux) {
  if (threadIdx.x == 0 && blockIdx.x == 0) {
    int acc = 0;
    for (int b = 0; b < 16; ++b) {
      tileOff[b] = acc;
      acc += (int)((counts[b] + 127u) >> 7);
    }
    tileOff[16] = acc;
    float a = 0.f;
    for (int e = 0; e < 8; ++e) {
      float load = (float)(counts[e] + counts[8 + e]) / (float)PAIRS;
      a += (impSum[e] / (float)T_TOKENS) * load;
    }
    out_aux[0] = a * (float)N_EXPERTS;
  }
}

// ---------------- bucket pairs (expert x slot) ----------------
__global__ __launch_bounds__(256) void moe_assign_kernel(
    const int* __restrict__ topi, const int* __restrict__ tileOff,
    unsigned int* __restrict__ cursors, int* __restrict__ row2pair) {
  int p = blockIdx.x * 256 + threadIdx.x;
  if (p >= PAIRS) return;
  int b = topi[p] + 8 * (p & 1);
  unsigned int pos = atomicAdd(&cursors[b], 1u);
  row2pair[tileOff[b] * 128 + (int)pos] = p;
}

// ======================= GEMM stages =======================
// BM=128 A-rows, BN=128 B-rows, BK=64, 4 waves (2M x 2N, wave tile 64x64).
// m97-proven SINGLE-buffer structure (32 KB LDS): stage 8 gll16 -> vmcnt(0)
// -> barrier -> 2 ks x (8 ds_read_b128 + 16 MFMA) -> barrier.  At 88 VGPR /
// 33 KB LDS this runs 4 blocks/CU (16 waves) -- wave-level overlap across
// independent blocks hides the drain (m114); dbuf at 2 blocks/CU measured
// WORSE (r11: 26% MfmaUtil vs m97-class 37%).
// LDS rows = 128B, XOR-8 chunk swizzle (0-conflict, proven r2/r9/r11):
//   slot(row,kc) = kc ^ (row&7); read slot = (ks*4+grp) ^ (lane&7).
// gll16: dest linear (base+lane*16), offset imm 0; 8 adjacent lanes read one
// row's 128B contiguously (src chunk = (lane&7)^sub) -> fully coalesced.
// Ticket order nt-fastest: consecutive items share the A-panel and expert
// B-panel -> L2/L3 locality.
// Stage A: NK = H/64 = 32.  Stage B: NK = I/64 = 16.

// ---------------- Stage A: P = silu(X@gate^T) * (X@up^T) ----------------
// BN=128 B-rows = 64 I-cols as gate|up: B-row (wq=brow>>6, r6=brow&63) is
// gate (r6<32) or up (r6>=32) of I-col nt*64 + wq*32 + (r6&31).
// Wave wn reads rows wn*64+n*16+lrow: n<2 gate, n>=2 up of the SAME col ->
// silu fuse in-register: acc[m][n] gate, acc[m][n+2] up.
__global__ __launch_bounds__(256, 4) void moe_stage_a(
    const unsigned short* __restrict__ Xb,
    const unsigned short* __restrict__ Wg, const unsigned short* __restrict__ Wu,
    const int* __restrict__ row2pair, const int* __restrict__ tileOff,
    unsigned int* __restrict__ workCtr, unsigned short* __restrict__ P) {
  __shared__ __align__(16) unsigned short sAB[16384];  // A [0,8192) B [8192,16384)
  __shared__ int sTok[128];
  __shared__ int sWork;
  const int tid = threadIdx.x;
  const int lane = tid & 63, w = tid >> 6;
  const int wm = w >> 1, wn = w & 1;
  const int lrow = lane & 15, grp = lane >> 4;
  const int sub = lane >> 3;
  const int kcs = ((lane & 7) ^ sub) << 3;   // src chunk offset (shorts)
  const int cx = (lane & 7) << 3;            // read-side XOR operand (shorts)
  const int nTiles = tileOff[16];
  const int nWork = nTiles * 16;

  for (;;) {
    if (tid == 0) sWork = (int)atomicAdd(workCtr, 1u);
    __syncthreads();
    const int item = sWork;
    if (item >= nWork) break;
    const int mt = item >> 4;           // nt fastest: consecutive items share A
    const int nt = item & 15;           // I-block [nt*64, nt*64+64)
    int b = 0;
#pragma unroll
    for (int k = 1; k < 16; ++k) if (tileOff[k] <= mt) b = k;
    const int e = b & 7;
    const int row0 = mt * 128;
    if (tid < 128) {
      int pr = row2pair[row0 + tid];
      sTok[tid] = (pr >= 0) ? (pr >> 1) : 0;
    }
    __syncthreads();

    const size_t wbase = (size_t)e * ((size_t)I_DIM * H_DIM);
    const unsigned short* src[8];
#pragma unroll
    for (int i = 0; i < 4; ++i) {            // A: row = i*32 + 8w + sub
      int row = i * 32 + 8 * w + sub;
      src[i] = Xb + (size_t)sTok[row] * H_DIM + kcs;
    }
#pragma unroll
    for (int i = 4; i < 8; ++i) {            // B: brow = (i-4)*32 + 8w + sub
      int brow = (i - 4) * 32 + 8 * w + sub;
      int wq = brow >> 6, r6 = brow & 63;
      int ic = nt * 64 + wq * 32 + (r6 & 31);
      const unsigned short* bp = (r6 & 32) ? Wu : Wg;
      src[i] = bp + wbase + (size_t)ic * H_DIM + kcs;
    }

    f32x4 acc[4][4] = {};

#pragma unroll 1
    for (int kk = 0; kk < 32; ++kk) {        // 32 * BK64 = 2048 = H_DIM
#pragma unroll
      for (int i = 0; i < 8; ++i)
        gll16(src[i] + (kk << 6), (void*)&sAB[(i * 256 + tid) * 8]);
      SB0();
      asm volatile("s_waitcnt vmcnt(0)" ::: "memory");
      SB0();
      BAR();
      SB0();
#pragma unroll
      for (int ks = 0; ks < 2; ++ks) {
        const int co = ((ks * 4 + grp) << 3) ^ cx;
        bfv af[4], bf[4];
#pragma unroll
        for (int m = 0; m < 4; ++m)
          af[m] = *reinterpret_cast<const bfv*>(
              &sAB[(wm * 64 + m * 16 + lrow) * 64 + co]);
#pragma unroll
        for (int n = 0; n < 4; ++n)
          bf[n] = *reinterpret_cast<const bfv*>(
              &sAB[8192 + (wn * 64 + n * 16 + lrow) * 64 + co]);
        __builtin_amdgcn_s_setprio(1);
#pragma unroll
        for (int m = 0; m < 4; ++m)
#pragma unroll
          for (int n = 0; n < 4; ++n)
            acc[m][n] = __builtin_amdgcn_mfma_f32_16x16x32_bf16(af[m], bf[n], acc[m][n], 0, 0, 0);
        __builtin_amdgcn_s_setprio(0);
      }
      SB0();
      BAR();
    }

    // epilogue: silu fuse; C/D: row = grp*4+j, col = lrow
#pragma unroll
    for (int m = 0; m < 4; ++m) {
#pragma unroll
      for (int n = 0; n < 2; ++n) {
#pragma unroll
        for (int j = 0; j < 4; ++j) {
          float g = acc[m][n][j];
          float uu = acc[m][n + 2][j];
          float pv = (g / (1.f + expf(-g))) * uu;
          int row = row0 + wm * 64 + m * 16 + grp * 4 + j;
          int col = nt * 64 + wn * 32 + n * 16 + lrow;
          P[(size_t)row * I_DIM + col] = f2bf(pv);
        }
      }
    }
  }
}

// ---------------- Stage B (one-shot): O = P @ down^T -> Opairs (bf16) ----------------
__global__ __launch_bounds__(256, 4) void moe_stage_b(
    const unsigned short* __restrict__ Pb, const unsigned short* __restrict__ Wd,
    const int* __restrict__ row2pair, const int* __restrict__ tileOff,
    unsigned int* __restrict__ workCtr, unsigned short* __restrict__ Opairs) {
  __shared__ __align__(16) unsigned short sAB[16384];
  __shared__ int sPair[128];
  __shared__ int sWork;
  const int tid = threadIdx.x;
  const int lane = tid & 63, w = tid >> 6;
  const int wm = w >> 1, wn = w & 1;
  const int lrow = lane & 15, grp = lane >> 4;
  const int sub = lane >> 3;
  const int kcs = ((lane & 7) ^ sub) << 3;
  const int cx = (lane & 7) << 3;
  const int nTiles = tileOff[16];
  const int nWork = nTiles * 16;

  for (;;) {
    if (tid == 0) sWork = (int)atomicAdd(workCtr, 1u);
    __syncthreads();
    const int item = sWork;
    if (item >= nWork) break;
    const int mt = item >> 4;           // nt fastest
    const int nt = item & 15;           // H-block [nt*128, nt*128+128)
    int b = 0;
#pragma unroll
    for (int k = 1; k < 16; ++k) if (tileOff[k] <= mt) b = k;
    const int e = b & 7;
    const int row0 = mt * 128, h0 = nt * 128;
    if (tid < 128) sPair[tid] = row2pair[row0 + tid];
    __syncthreads();

    const unsigned short* src[8];
#pragma unroll
    for (int i = 0; i < 4; ++i) {
      int row = i * 32 + 8 * w + sub;
      src[i] = Pb + (size_t)(row0 + row) * I_DIM + kcs;
    }
#pragma unroll
    for (int i = 4; i < 8; ++i) {
      int brow = (i - 4) * 32 + 8 * w + sub;
      src[i] = Wd + (size_t)e * ((size_t)H_DIM * I_DIM) + (size_t)(h0 + brow) * I_DIM + kcs;
    }

    f32x4 acc[4][4] = {};

#pragma unroll 1
    for (int kk = 0; kk < 16; ++kk) {        // 16 * BK64 = 1024 = I_DIM
#pragma unroll
      for (int i = 0; i < 8; ++i)
        gll16(src[i] + (kk << 6), (void*)&sAB[(i * 256 + tid) * 8]);
      SB0();
      asm volatile("s_waitcnt vmcnt(0)" ::: "memory");
      SB0();
      BAR();
      SB0();
#pragma unroll
      for (int ks = 0; ks < 2; ++ks) {
        const int co = ((ks * 4 + grp) << 3) ^ cx;
        bfv af[4], bf[4];
#pragma unroll
        for (int m = 0; m < 4; ++m)
          af[m] = *reinterpret_cast<const bfv*>(
              &sAB[(wm * 64 + m * 16 + lrow) * 64 + co]);
#pragma unroll
        for (int n = 0; n < 4; ++n)
          bf[n] = *reinterpret_cast<const bfv*>(
              &sAB[8192 + (wn * 64 + n * 16 + lrow) * 64 + co]);
        __builtin_amdgcn_s_setprio(1);
#pragma unroll
        for (int m = 0; m < 4; ++m)
#pragma unroll
          for (int n = 0; n < 4; ++n)
            acc[m][n] = __builtin_amdgcn_mfma_f32_16x16x32_bf16(af[m], bf[n], acc[m][n], 0, 0, 0);
        __builtin_amdgcn_s_setprio(0);
      }
      SB0();
      BAR();
    }

#pragma unroll
    for (int m = 0; m < 4; ++m) {
#pragma unroll
      for (int j = 0; j < 4; ++j) {
        int rl = wm * 64 + m * 16 + grp * 4 + j;
        int pr = sPair[rl];
        if (pr < 0) continue;
        unsigned short* orow = Opairs + (size_t)pr * H_DIM + h0 + wn * 64 + lrow;
#pragma unroll
        for (int n = 0; n < 4; ++n) orow[n * 16] = f2bf(acc[m][n][j]);
      }
    }
  }
}

// ---------------- Combine: out[t] = 4 * (w0*O[2t] + w1*O[2t+1]) ----------------
__global__ __launch_bounds__(256) void moe_combine_kernel(
    const unsigned short* __restrict__ Opairs, const float* __restrict__ topw,
    float* __restrict__ out) {
  size_t g = (size_t)blockIdx.x * 256 + threadIdx.x;
  size_t base = g * 8;
  int t = (int)(base >> 11);
  int h = (int)(base & 2047);
  float w0 = topw[t * 2] * 4.f;
  float w1 = topw[t * 2 + 1] * 4.f;
  u16x8 o0 = *reinterpret_cast<const u16x8*>(Opairs + (size_t)(t * 2) * H_DIM + h);
  u16x8 o1 = *reinterpret_cast<const u16x8*>(Opairs + (size_t)(t * 2 + 1) * H_DIM + h);
  f32x4 r0, r1;
#pragma unroll
  for (int j = 0; j < 4; ++j) r0[j] = w0 * bf2f(o0[j]) + w1 * bf2f(o1[j]);
#pragma unroll
  for (int j = 0; j < 4; ++j) r1[j] = w0 * bf2f(o0[4 + j]) + w1 * bf2f(o1[4 + j]);
  *reinterpret_cast<f32x4*>(out + base) = r0;
  *reinterpret_cast<f32x4*>(out + base + 4) = r1;
}

// ---------------- launch ----------------
// ws layout (bytes), REQ = 138,879,488 (proven); REQ3 = 172,433,920 (gated):
//   P        @ 0           : 18432*1024*2 = 37,748,736
//   probs    @ 37,748,736  : 262,144
//   topw     @ 38,010,880  : 65,536
//   topi     @ 38,076,416  : 65,536
//   row2pair @ 38,141,952  : 73,728
//   ctrl     @ 38,215,680  : 512
//   W1       @ 38,216,192  : 33,554,432  (gate bf16; down bf16 in fallback)
//   W2       @ 71,770,624  : 33,554,432  (up bf16)
//   Xb       @ 105,325,056 : 33,554,432  (X bf16)
//   Opairs   @ 71,770,624  : 67,108,864  (overlays W2+Xb; both dead in stage B)
//   W3       @ 138,879,488 : 33,554,432  (down bf16, only if ws_size >= REQ3)
extern "C" void kernel_launch(void* const* d_in, const int* in_sizes, int n_in,
                              void* d_out, int out_size, void* d_ws, size_t ws_size,
                              hipStream_t stream) {
  const float* X = (const float*)d_in[0];
  const float* norm_w = (const float*)d_in[1];
  const float* router_w = (const float*)d_in[2];
  const float* gate_w = (const float*)d_in[3];
  const float* up_w = (const float*)d_in[4];
  const float* down_w = (const float*)d_in[5];
  float* out = (float*)d_out;

  char* ws = (char*)d_ws;
  unsigned short* P = (unsigned short*)(ws);
  float* probs = (float*)(ws + 37748736);
  float* topw = (float*)(ws + 38010880);
  int* topi = (int*)(ws + 38076416);
  int* row2pair = (int*)(ws + 38141952);
  char* ctrl = ws + 38215680;
  unsigned int* counts = (unsigned int*)(ctrl);
  unsigned int* cursors = (unsigned int*)(ctrl + 64);
  float* impSum = (float*)(ctrl + 128);
  int* tileOff = (int*)(ctrl + 192);
  unsigned int* wcA = (unsigned int*)(ctrl + 384);
  unsigned int* wcB = (unsigned int*)(ctrl + 388);
  unsigned short* W1 = (unsigned short*)(ws + 38216192);
  unsigned short* W2 = (unsigned short*)(ws + 71770624);
  unsigned short* Xb = (unsigned short*)(ws + 105325056);
  unsigned short* Opairs = (unsigned short*)(ws + 71770624);
  unsigned short* W3 = (unsigned short*)(ws + 138879488);
  const bool w3ok = ws_size >= 172433920ull;

  hipMemsetAsync(ctrl, 0, 512, stream);
  hipMemsetAsync(row2pair, 0xFF, (size_t)TOT_ROWS * 4, stream);

  moe_router_kernel<<<T_TOKENS, 256, 0, stream>>>(
      X, norm_w, router_w, probs, topw, topi, counts, Xb,
      gate_w, up_w, down_w, W1, W2, w3ok ? W3 : nullptr);
  moe_importance_kernel<<<N_EXPERTS, 256, 0, stream>>>(probs, impSum);
  moe_offsets_aux_kernel<<<1, 64, 0, stream>>>(counts, impSum, tileOff, out + 16777216);
  moe_assign_kernel<<<PAIRS / 256, 256, 0, stream>>>(topi, tileOff, cursors, row2pair);

  moe_stage_a<<<1024, 256, 0, stream>>>(Xb, W1, W2, row2pair, tileOff, wcA, P);

  const unsigned short* DW = W3;
  if (!w3ok) {
    const int N8 = (N_EXPERTS * I_DIM * H_DIM) / 8;   // 2,097,152
    moe_convert_kernel<<<N8 / 256, 256, 0, stream>>>(down_w, W1, N8);  // gate dead
    DW = W1;
  }
  moe_stage_b<<<1024, 256, 0, stream>>>(P, DW, row2pair, tileOff, wcB, Opairs);
  moe_combine_kernel<<<T_TOKENS, 256, 0, stream>>>(Opairs, topw, out);
}